// Round 1
// baseline (688.603 us; speedup 1.0000x reference)
//
#include <hip/hip_runtime.h>

#define F_DIM   128
#define HC      128
#define NSLOPE  0.2f

// ---------------- Kernel 1: h = x @ W^T, fused attention dots ----------------
// W (128x128) staged in LDS padded to stride 132 (conflict-free float4 reads).
// Each wave processes 4 nodes per iteration; lane l owns channels l and l+64.
__global__ __launch_bounds__(256) void k_gemm_att(
    const float* __restrict__ x, const float* __restrict__ Wg,
    const float* __restrict__ att_src, const float* __restrict__ att_dst,
    float* __restrict__ h, float* __restrict__ a_src, float* __restrict__ a_dst,
    int N)
{
    __shared__ float Wl[128 * 132];
    __shared__ float xl[4][4][128];

    const int t = threadIdx.x;
    const int wave = t >> 6, l = t & 63;

    // stage W: 128x128 floats as float4, coalesced
    for (int i = t; i < 128 * 32; i += 256) {
        int r = i >> 5, c4 = (i & 31) * 4;
        float4 w = *(const float4*)(Wg + r * 128 + c4);
        *(float4*)(&Wl[r * 132 + c4]) = w;
    }

    const float as0 = att_src[l],      as1 = att_src[64 + l];
    const float ad0 = att_dst[l],      ad1 = att_dst[64 + l];

    __syncthreads();

    const int stride = gridDim.x * 16;
    for (int cb = blockIdx.x * 16; cb < N; cb += stride) {
        const int nb = cb + wave * 4;   // this wave's 4 nodes
        // stage x rows (4 per wave): lane loads 2 float4
        {
            int r0 = (4 * l) >> 7, c0 = (4 * l) & 127;
            int n0 = nb + r0;
            float4 v0 = (n0 < N) ? *(const float4*)(x + (size_t)n0 * 128 + c0)
                                 : make_float4(0.f, 0.f, 0.f, 0.f);
            *(float4*)(&xl[wave][r0][c0]) = v0;
            int r1 = r0 + 2;
            int n1 = nb + r1;
            float4 v1 = (n1 < N) ? *(const float4*)(x + (size_t)n1 * 128 + c0)
                                 : make_float4(0.f, 0.f, 0.f, 0.f);
            *(float4*)(&xl[wave][r1][c0]) = v1;
        }
        __syncthreads();

        float acc[4][2];
        #pragma unroll
        for (int i = 0; i < 4; ++i) { acc[i][0] = 0.f; acc[i][1] = 0.f; }

        const float* wr0 = &Wl[(size_t)l * 132];
        const float* wr1 = &Wl[(size_t)(l + 64) * 132];

        #pragma unroll 8
        for (int f = 0; f < 128; f += 4) {
            float4 w0 = *(const float4*)(wr0 + f);
            float4 w1 = *(const float4*)(wr1 + f);
            #pragma unroll
            for (int i = 0; i < 4; ++i) {
                float4 xv = *(const float4*)(&xl[wave][i][f]);
                acc[i][0] += xv.x * w0.x + xv.y * w0.y + xv.z * w0.z + xv.w * w0.w;
                acc[i][1] += xv.x * w1.x + xv.y * w1.y + xv.z * w1.z + xv.w * w1.w;
            }
        }

        #pragma unroll
        for (int i = 0; i < 4; ++i) {
            int node = nb + i;
            if (node >= N) continue;   // uniform across the wave
            float h0 = acc[i][0], h1 = acc[i][1];
            h[(size_t)node * 128 + l]      = h0;
            h[(size_t)node * 128 + 64 + l] = h1;
            // attention dots: reduce within 32-lane halves
            float ps = h0 * as0, pd = h0 * ad0;   // heads (l>>5) -> 0/1
            float qs = h1 * as1, qd = h1 * ad1;   // heads 2+(l>>5) -> 2/3
            #pragma unroll
            for (int m = 1; m < 32; m <<= 1) {
                ps += __shfl_xor(ps, m); pd += __shfl_xor(pd, m);
                qs += __shfl_xor(qs, m); qd += __shfl_xor(qd, m);
            }
            if (l == 0) {
                a_src[node * 4 + 0] = ps; a_dst[node * 4 + 0] = pd;
                a_src[node * 4 + 2] = qs; a_dst[node * 4 + 2] = qd;
            } else if (l == 32) {
                a_src[node * 4 + 1] = ps; a_dst[node * 4 + 1] = pd;
                a_src[node * 4 + 3] = qs; a_dst[node * 4 + 3] = qd;
            }
        }
        __syncthreads();
    }
}

// ---------------- Kernel 2: in-degree histogram ----------------
__global__ void k_hist(const int* __restrict__ dst, int* __restrict__ deg, int E)
{
    int i = blockIdx.x * blockDim.x + threadIdx.x;
    int stride = gridDim.x * blockDim.x;
    for (; i < E; i += stride) atomicAdd(&deg[dst[i]], 1);
}

// ---------------- Kernel 3: single-block exclusive scan ----------------
__global__ __launch_bounds__(1024) void k_scan(
    const int* __restrict__ deg, int* __restrict__ rowptr,
    int* __restrict__ cursor, int N)
{
    __shared__ int sums[1024];
    const int t = threadIdx.x;
    const int chunk = (N + 1023) / 1024;
    const int lo = t * chunk;
    const int hi = min(lo + chunk, N);

    int s = 0;
    for (int i = lo; i < hi; ++i) s += deg[i];
    sums[t] = s;
    __syncthreads();

    for (int off = 1; off < 1024; off <<= 1) {
        int v = sums[t];
        int u = (t >= off) ? sums[t - off] : 0;
        __syncthreads();
        sums[t] = v + u;
        __syncthreads();
    }

    int run = (t == 0) ? 0 : sums[t - 1];
    for (int i = lo; i < hi; ++i) {
        rowptr[i] = run; cursor[i] = run;
        run += deg[i];
    }
    if (t == 1023) rowptr[N] = sums[1023];
}

// ---------------- Kernel 4: scatter src ids into CSR ----------------
__global__ void k_scatter(const int* __restrict__ ei, int* __restrict__ cursor,
                          int* __restrict__ csr, int E)
{
    int i = blockIdx.x * blockDim.x + threadIdx.x;
    int stride = gridDim.x * blockDim.x;
    for (; i < E; i += stride) {
        int s = ei[i];
        int d = ei[E + i];
        int pos = atomicAdd(&cursor[d], 1);
        csr[pos] = s;
    }
}

// ---------------- Kernel 5: per-node softmax-aggregate + fused classifier ----
// One wave per node. No max-subtraction needed (e ~ N(0,2), exp is safe in fp32).
__global__ __launch_bounds__(256) void k_agg(
    const float* __restrict__ h, const float* __restrict__ a_src,
    const float* __restrict__ a_dst, const int* __restrict__ rowptr,
    const int* __restrict__ csr, const float* __restrict__ b_gat,
    const float* __restrict__ W_lin, const float* __restrict__ b_lin,
    float* __restrict__ out, int N)
{
    const int t = threadIdx.x;
    const int wave = t >> 6, l = t & 63;
    const int n = blockIdx.x * 4 + wave;
    if (n >= N) return;

    const int start = rowptr[n], end = rowptr[n + 1];

    // ---- denominator pass: lanes cover (16 edges) x (4 heads) ----
    const int hq = l & 3;
    const float ad_q = a_dst[n * 4 + hq];
    float part = 0.f;
    for (int i = start + (l >> 2); i < end; i += 16) {
        int s = csr[i];
        float e = a_src[s * 4 + hq] + ad_q;
        e = (e >= 0.f) ? e : NSLOPE * e;
        part += __expf(e);
    }
    // self-loop term for head hq
    float es = a_src[n * 4 + hq] + ad_q;
    es = (es >= 0.f) ? es : NSLOPE * es;
    const float exps = __expf(es);

    part += __shfl_xor(part, 4);
    part += __shfl_xor(part, 8);
    part += __shfl_xor(part, 16);
    part += __shfl_xor(part, 32);
    part += exps;   // every lane now holds denom for head (l&3)

    const int hA = l >> 5, hB = 2 + (l >> 5);
    const float denA = __shfl(part, hA);
    const float denB = __shfl(part, hB);
    const float expsA = __shfl(exps, hA);
    const float expsB = __shfl(exps, hB);
    const float invA = 1.f / denA;
    const float invB = 1.f / denB;
    const float adA = a_dst[n * 4 + hA];
    const float adB = a_dst[n * 4 + hB];

    // ---- weighted accumulation: self loop first ----
    float acc0 = (expsA * invA) * h[(size_t)n * 128 + l];
    float acc1 = (expsB * invB) * h[(size_t)n * 128 + 64 + l];

    int i = start;
    for (; i + 1 < end; i += 2) {   // 2-way unroll for ILP
        int s0 = csr[i], s1 = csr[i + 1];
        float eA0 = a_src[s0 * 4 + hA] + adA; eA0 = (eA0 >= 0.f) ? eA0 : NSLOPE * eA0;
        float eB0 = a_src[s0 * 4 + hB] + adB; eB0 = (eB0 >= 0.f) ? eB0 : NSLOPE * eB0;
        float eA1 = a_src[s1 * 4 + hA] + adA; eA1 = (eA1 >= 0.f) ? eA1 : NSLOPE * eA1;
        float eB1 = a_src[s1 * 4 + hB] + adB; eB1 = (eB1 >= 0.f) ? eB1 : NSLOPE * eB1;
        float alA0 = __expf(eA0) * invA, alB0 = __expf(eB0) * invB;
        float alA1 = __expf(eA1) * invA, alB1 = __expf(eB1) * invB;
        float v00 = h[(size_t)s0 * 128 + l], v01 = h[(size_t)s0 * 128 + 64 + l];
        float v10 = h[(size_t)s1 * 128 + l], v11 = h[(size_t)s1 * 128 + 64 + l];
        acc0 += alA0 * v00 + alA1 * v10;
        acc1 += alB0 * v01 + alB1 * v11;
    }
    if (i < end) {
        int s0 = csr[i];
        float eA0 = a_src[s0 * 4 + hA] + adA; eA0 = (eA0 >= 0.f) ? eA0 : NSLOPE * eA0;
        float eB0 = a_src[s0 * 4 + hB] + adB; eB0 = (eB0 >= 0.f) ? eB0 : NSLOPE * eB0;
        acc0 += (__expf(eA0) * invA) * h[(size_t)s0 * 128 + l];
        acc1 += (__expf(eB0) * invB) * h[(size_t)s0 * 128 + 64 + l];
    }

    // ---- fused epilogue: +b_gat, ReLU, Linear(128->2), wave reduce ----
    float r0 = fmaxf(acc0 + b_gat[l], 0.f);
    float r1 = fmaxf(acc1 + b_gat[64 + l], 0.f);
    float p0 = r0 * W_lin[l]       + r1 * W_lin[64 + l];
    float p1 = r0 * W_lin[128 + l] + r1 * W_lin[192 + l];
    #pragma unroll
    for (int m = 1; m < 64; m <<= 1) {
        p0 += __shfl_xor(p0, m);
        p1 += __shfl_xor(p1, m);
    }
    if (l == 0) {
        out[(size_t)n * 2]     = p0 + b_lin[0];
        out[(size_t)n * 2 + 1] = p1 + b_lin[1];
    }
}

// ---------------- launch ----------------
extern "C" void kernel_launch(void* const* d_in, const int* in_sizes, int n_in,
                              void* d_out, int out_size, void* d_ws, size_t ws_size,
                              hipStream_t stream)
{
    const float* x       = (const float*)d_in[0];
    const int*   ei      = (const int*)d_in[1];
    const float* Wg      = (const float*)d_in[2];
    const float* att_src = (const float*)d_in[3];
    const float* att_dst = (const float*)d_in[4];
    const float* b_gat   = (const float*)d_in[5];
    const float* W_lin   = (const float*)d_in[6];
    const float* b_lin   = (const float*)d_in[7];
    float* out = (float*)d_out;

    const int N = in_sizes[0] / 128;
    const int E = in_sizes[1] / 2;

    // workspace layout (all 4-byte aligned; float4 regions 16B aligned)
    char* ws = (char*)d_ws;
    float* h      = (float*)ws;                       // N*128 floats
    float* a_src  = h + (size_t)N * 128;              // N*4
    float* a_dst  = a_src + (size_t)N * 4;            // N*4
    int*   deg    = (int*)(a_dst + (size_t)N * 4);    // N
    int*   rowptr = deg + N;                          // N+1
    int*   cursor = rowptr + (N + 1);                 // N
    int*   csr    = cursor + N;                       // E

    hipMemsetAsync(deg, 0, (size_t)N * sizeof(int), stream);

    k_gemm_att<<<512, 256, 0, stream>>>(x, Wg, att_src, att_dst, h, a_src, a_dst, N);
    k_hist<<<2048, 256, 0, stream>>>(ei + E, deg, E);
    k_scan<<<1, 1024, 0, stream>>>(deg, rowptr, cursor, N);
    k_scatter<<<2048, 256, 0, stream>>>(ei, cursor, csr, E);
    k_agg<<<(N + 3) / 4, 256, 0, stream>>>(h, a_src, a_dst, rowptr, csr,
                                           b_gat, W_lin, b_lin, out, N);
}

// Round 2
// 465.661 us; speedup vs baseline: 1.4788x; 1.4788x over previous
//
#include <hip/hip_runtime.h>

#define NSLOPE  0.2f

// ---------------- Kernel 1: h = x @ W^T, fused attention dots ----------------
// W (128x128) staged in LDS padded to stride 132 (conflict-free float4 reads).
// Each wave processes 4 nodes per iteration; lane l owns channels l and l+64.
__global__ __launch_bounds__(256) void k_gemm_att(
    const float* __restrict__ x, const float* __restrict__ Wg,
    const float* __restrict__ att_src, const float* __restrict__ att_dst,
    float* __restrict__ h, float* __restrict__ a_src, float* __restrict__ a_dst,
    int N)
{
    __shared__ float Wl[128 * 132];
    __shared__ float xl[4][4][128];

    const int t = threadIdx.x;
    const int wave = t >> 6, l = t & 63;

    // stage W: 128x128 floats as float4, coalesced
    for (int i = t; i < 128 * 32; i += 256) {
        int r = i >> 5, c4 = (i & 31) * 4;
        float4 w = *(const float4*)(Wg + r * 128 + c4);
        *(float4*)(&Wl[r * 132 + c4]) = w;
    }

    const float as0 = att_src[l],      as1 = att_src[64 + l];
    const float ad0 = att_dst[l],      ad1 = att_dst[64 + l];

    __syncthreads();

    const int stride = gridDim.x * 16;
    for (int cb = blockIdx.x * 16; cb < N; cb += stride) {
        const int nb = cb + wave * 4;   // this wave's 4 nodes
        // stage x rows (4 per wave): lane loads 2 float4
        {
            int r0 = (4 * l) >> 7, c0 = (4 * l) & 127;
            int n0 = nb + r0;
            float4 v0 = (n0 < N) ? *(const float4*)(x + (size_t)n0 * 128 + c0)
                                 : make_float4(0.f, 0.f, 0.f, 0.f);
            *(float4*)(&xl[wave][r0][c0]) = v0;
            int r1 = r0 + 2;
            int n1 = nb + r1;
            float4 v1 = (n1 < N) ? *(const float4*)(x + (size_t)n1 * 128 + c0)
                                 : make_float4(0.f, 0.f, 0.f, 0.f);
            *(float4*)(&xl[wave][r1][c0]) = v1;
        }
        __syncthreads();

        float acc[4][2];
        #pragma unroll
        for (int i = 0; i < 4; ++i) { acc[i][0] = 0.f; acc[i][1] = 0.f; }

        const float* wr0 = &Wl[(size_t)l * 132];
        const float* wr1 = &Wl[(size_t)(l + 64) * 132];

        #pragma unroll 8
        for (int f = 0; f < 128; f += 4) {
            float4 w0 = *(const float4*)(wr0 + f);
            float4 w1 = *(const float4*)(wr1 + f);
            #pragma unroll
            for (int i = 0; i < 4; ++i) {
                float4 xv = *(const float4*)(&xl[wave][i][f]);
                acc[i][0] += xv.x * w0.x + xv.y * w0.y + xv.z * w0.z + xv.w * w0.w;
                acc[i][1] += xv.x * w1.x + xv.y * w1.y + xv.z * w1.z + xv.w * w1.w;
            }
        }

        #pragma unroll
        for (int i = 0; i < 4; ++i) {
            int node = nb + i;
            if (node >= N) continue;   // uniform across the wave
            float h0 = acc[i][0], h1 = acc[i][1];
            h[(size_t)node * 128 + l]      = h0;
            h[(size_t)node * 128 + 64 + l] = h1;
            // attention dots: reduce within 32-lane halves
            float ps = h0 * as0, pd = h0 * ad0;   // heads (l>>5) -> 0/1
            float qs = h1 * as1, qd = h1 * ad1;   // heads 2+(l>>5) -> 2/3
            #pragma unroll
            for (int m = 1; m < 32; m <<= 1) {
                ps += __shfl_xor(ps, m); pd += __shfl_xor(pd, m);
                qs += __shfl_xor(qs, m); qd += __shfl_xor(qd, m);
            }
            if (l == 0) {
                a_src[node * 4 + 0] = ps; a_dst[node * 4 + 0] = pd;
                a_src[node * 4 + 2] = qs; a_dst[node * 4 + 2] = qd;
            } else if (l == 32) {
                a_src[node * 4 + 1] = ps; a_dst[node * 4 + 1] = pd;
                a_src[node * 4 + 3] = qs; a_dst[node * 4 + 3] = qd;
            }
        }
        __syncthreads();
    }
}

// ---------------- Kernel 2: in-degree histogram ----------------
__global__ void k_hist(const int* __restrict__ dst, int* __restrict__ deg, int E)
{
    int i = blockIdx.x * blockDim.x + threadIdx.x;
    int stride = gridDim.x * blockDim.x;
    for (; i < E; i += stride) atomicAdd(&deg[dst[i]], 1);
}

// ---------------- Kernel 3a: per-block local exclusive scan (1024 elems/block)
__global__ __launch_bounds__(256) void k_scan_local(
    const int* __restrict__ deg, int* __restrict__ loc,
    int* __restrict__ partial, int N)
{
    __shared__ int wsum[4];
    const int t = threadIdx.x;
    const int base = blockIdx.x * 1024 + t * 4;

    int v0 = 0, v1 = 0, v2 = 0, v3 = 0;
    if (base + 3 < N) {
        int4 d = *(const int4*)(deg + base);
        v0 = d.x; v1 = d.y; v2 = d.z; v3 = d.w;
    } else if (base < N) {
        v0 = deg[base];
        if (base + 1 < N) v1 = deg[base + 1];
        if (base + 2 < N) v2 = deg[base + 2];
    }
    const int s = v0 + v1 + v2 + v3;

    // inclusive wave scan of per-thread sums
    const int l = t & 63;
    int sc = s;
    #pragma unroll
    for (int m = 1; m < 64; m <<= 1) {
        int u = __shfl_up(sc, m);
        if (l >= m) sc += u;
    }
    if (l == 63) wsum[t >> 6] = sc;
    __syncthreads();

    int woff = 0;
    const int w = t >> 6;
    #pragma unroll
    for (int i = 0; i < 4; ++i) if (i < w) woff += wsum[i];

    const int excl = woff + sc - s;   // exclusive prefix of this thread's 4
    if (base < N) {
        int o0 = excl, o1 = o0 + v0, o2 = o1 + v1, o3 = o2 + v2;
        if (base + 3 < N) {
            *(int4*)(loc + base) = make_int4(o0, o1, o2, o3);
        } else {
            loc[base] = o0;
            if (base + 1 < N) loc[base + 1] = o1;
            if (base + 2 < N) loc[base + 2] = o2;
        }
    }
    if (t == 255) partial[blockIdx.x] = woff + sc;   // block total
}

// ---------------- Kernel 3b: single-wave scan of block totals ----------------
__global__ __launch_bounds__(64) void k_scan_part(
    int* __restrict__ partial, int* __restrict__ total_out, int nb)
{
    const int l = threadIdx.x;
    int carry = 0;
    for (int base = 0; base < nb; base += 64) {
        int i = base + l;
        int v = (i < nb) ? partial[i] : 0;
        int sc = v;
        #pragma unroll
        for (int m = 1; m < 64; m <<= 1) {
            int u = __shfl_up(sc, m);
            if (l >= m) sc += u;
        }
        if (i < nb) partial[i] = carry + sc - v;   // exclusive
        carry += __shfl(sc, 63);
    }
    if (l == 0) *total_out = carry;   // rowptr[N]
}

// ---------------- Kernel 3c: add block offsets, write rowptr & cursor -------
__global__ __launch_bounds__(256) void k_scan_add(
    const int* __restrict__ loc, const int* __restrict__ partial,
    int* __restrict__ rowptr, int* __restrict__ cursor, int N)
{
    const int off = partial[blockIdx.x];
    const int base = blockIdx.x * 1024 + threadIdx.x * 4;
    if (base + 3 < N) {
        int4 v = *(const int4*)(loc + base);
        v.x += off; v.y += off; v.z += off; v.w += off;
        *(int4*)(rowptr + base) = v;
        *(int4*)(cursor + base) = v;
    } else if (base < N) {
        for (int i = base; i < N && i < base + 4; ++i) {
            int v = loc[i] + off;
            rowptr[i] = v; cursor[i] = v;
        }
    }
}

// ---------------- Kernel 4: scatter src ids into CSR ----------------
__global__ void k_scatter(const int* __restrict__ ei, int* __restrict__ cursor,
                          int* __restrict__ csr, int E)
{
    int i = blockIdx.x * blockDim.x + threadIdx.x;
    int stride = gridDim.x * blockDim.x;
    for (; i < E; i += stride) {
        int s = ei[i];
        int d = ei[E + i];
        int pos = atomicAdd(&cursor[d], 1);
        csr[pos] = s;
    }
}

// ---------------- Kernel 5: per-node softmax-aggregate + fused classifier ----
// One wave per node. No max-subtraction needed (e ~ N(0,2), exp is safe in fp32).
__global__ __launch_bounds__(256) void k_agg(
    const float* __restrict__ h, const float* __restrict__ a_src,
    const float* __restrict__ a_dst, const int* __restrict__ rowptr,
    const int* __restrict__ csr, const float* __restrict__ b_gat,
    const float* __restrict__ W_lin, const float* __restrict__ b_lin,
    float* __restrict__ out, int N)
{
    const int t = threadIdx.x;
    const int wave = t >> 6, l = t & 63;
    const int n = blockIdx.x * 4 + wave;
    if (n >= N) return;

    const int start = rowptr[n], end = rowptr[n + 1];

    // ---- denominator pass: lanes cover (16 edges) x (4 heads) ----
    const int hq = l & 3;
    const float ad_q = a_dst[n * 4 + hq];
    float part = 0.f;
    for (int i = start + (l >> 2); i < end; i += 16) {
        int s = csr[i];
        float e = a_src[s * 4 + hq] + ad_q;
        e = (e >= 0.f) ? e : NSLOPE * e;
        part += __expf(e);
    }
    // self-loop term for head hq
    float es = a_src[n * 4 + hq] + ad_q;
    es = (es >= 0.f) ? es : NSLOPE * es;
    const float exps = __expf(es);

    part += __shfl_xor(part, 4);
    part += __shfl_xor(part, 8);
    part += __shfl_xor(part, 16);
    part += __shfl_xor(part, 32);
    part += exps;   // every lane now holds denom for head (l&3)

    const int hA = l >> 5, hB = 2 + (l >> 5);
    const float denA = __shfl(part, hA);
    const float denB = __shfl(part, hB);
    const float expsA = __shfl(exps, hA);
    const float expsB = __shfl(exps, hB);
    const float invA = 1.f / denA;
    const float invB = 1.f / denB;
    const float adA = a_dst[n * 4 + hA];
    const float adB = a_dst[n * 4 + hB];

    // ---- weighted accumulation: self loop first ----
    float acc0 = (expsA * invA) * h[(size_t)n * 128 + l];
    float acc1 = (expsB * invB) * h[(size_t)n * 128 + 64 + l];

    int i = start;
    for (; i + 1 < end; i += 2) {   // 2-way unroll for ILP
        int s0 = csr[i], s1 = csr[i + 1];
        float eA0 = a_src[s0 * 4 + hA] + adA; eA0 = (eA0 >= 0.f) ? eA0 : NSLOPE * eA0;
        float eB0 = a_src[s0 * 4 + hB] + adB; eB0 = (eB0 >= 0.f) ? eB0 : NSLOPE * eB0;
        float eA1 = a_src[s1 * 4 + hA] + adA; eA1 = (eA1 >= 0.f) ? eA1 : NSLOPE * eA1;
        float eB1 = a_src[s1 * 4 + hB] + adB; eB1 = (eB1 >= 0.f) ? eB1 : NSLOPE * eB1;
        float alA0 = __expf(eA0) * invA, alB0 = __expf(eB0) * invB;
        float alA1 = __expf(eA1) * invA, alB1 = __expf(eB1) * invB;
        float v00 = h[(size_t)s0 * 128 + l], v01 = h[(size_t)s0 * 128 + 64 + l];
        float v10 = h[(size_t)s1 * 128 + l], v11 = h[(size_t)s1 * 128 + 64 + l];
        acc0 += alA0 * v00 + alA1 * v10;
        acc1 += alB0 * v01 + alB1 * v11;
    }
    if (i < end) {
        int s0 = csr[i];
        float eA0 = a_src[s0 * 4 + hA] + adA; eA0 = (eA0 >= 0.f) ? eA0 : NSLOPE * eA0;
        float eB0 = a_src[s0 * 4 + hB] + adB; eB0 = (eB0 >= 0.f) ? eB0 : NSLOPE * eB0;
        acc0 += (__expf(eA0) * invA) * h[(size_t)s0 * 128 + l];
        acc1 += (__expf(eB0) * invB) * h[(size_t)s0 * 128 + 64 + l];
    }

    // ---- fused epilogue: +b_gat, ReLU, Linear(128->2), wave reduce ----
    float r0 = fmaxf(acc0 + b_gat[l], 0.f);
    float r1 = fmaxf(acc1 + b_gat[64 + l], 0.f);
    float p0 = r0 * W_lin[l]       + r1 * W_lin[64 + l];
    float p1 = r0 * W_lin[128 + l] + r1 * W_lin[192 + l];
    #pragma unroll
    for (int m = 1; m < 64; m <<= 1) {
        p0 += __shfl_xor(p0, m);
        p1 += __shfl_xor(p1, m);
    }
    if (l == 0) {
        out[(size_t)n * 2]     = p0 + b_lin[0];
        out[(size_t)n * 2 + 1] = p1 + b_lin[1];
    }
}

// ---------------- launch ----------------
extern "C" void kernel_launch(void* const* d_in, const int* in_sizes, int n_in,
                              void* d_out, int out_size, void* d_ws, size_t ws_size,
                              hipStream_t stream)
{
    const float* x       = (const float*)d_in[0];
    const int*   ei      = (const int*)d_in[1];
    const float* Wg      = (const float*)d_in[2];
    const float* att_src = (const float*)d_in[3];
    const float* att_dst = (const float*)d_in[4];
    const float* b_gat   = (const float*)d_in[5];
    const float* W_lin   = (const float*)d_in[6];
    const float* b_lin   = (const float*)d_in[7];
    float* out = (float*)d_out;

    const int N = in_sizes[0] / 128;
    const int E = in_sizes[1] / 2;
    const int NB = (N + 1023) / 1024;   // scan blocks

    // workspace layout (all 4-byte aligned; float4/int4 regions 16B aligned)
    char* ws = (char*)d_ws;
    float* h      = (float*)ws;                       // N*128 floats
    float* a_src  = h + (size_t)N * 128;              // N*4
    float* a_dst  = a_src + (size_t)N * 4;            // N*4
    int*   deg    = (int*)(a_dst + (size_t)N * 4);    // N
    int*   rowptr = deg + N;                          // N+1
    int*   cursor = rowptr + (N + 1) + 3;             // N  (16B-align)
    int*   csr    = cursor + N + 1;                   // E  (16B-align)
    int*   partial= csr + E;                          // NB
    int*   loc    = csr;   // alias: csr written only after loc consumed

    hipMemsetAsync(deg, 0, (size_t)N * sizeof(int), stream);

    k_gemm_att<<<512, 256, 0, stream>>>(x, Wg, att_src, att_dst, h, a_src, a_dst, N);
    k_hist<<<2048, 256, 0, stream>>>(ei + E, deg, E);
    k_scan_local<<<NB, 256, 0, stream>>>(deg, loc, partial, N);
    k_scan_part<<<1, 64, 0, stream>>>(partial, rowptr + N, NB);
    k_scan_add<<<NB, 256, 0, stream>>>(loc, partial, rowptr, cursor, N);
    k_scatter<<<2048, 256, 0, stream>>>(ei, cursor, csr, E);
    k_agg<<<(N + 3) / 4, 256, 0, stream>>>(h, a_src, a_dst, rowptr, csr,
                                           b_gat, W_lin, b_lin, out, N);
}